// Round 9
// baseline (201.270 us; speedup 1.0000x reference)
//
#include <hip/hip_runtime.h>
#include <math.h>

// Problem constants (from reference)
#define B_ 4
#define L_ 2048
#define R_ 1024
#define D_ 128      // ssm input dim
#define N_ 64       // state size
#define TWO_D 256   // 2*D
#define M_ (B_*L_)  // 8192 rows

// scan chunking: NC=32 chunks of TC=64 (R9: halves summary traffic + prefix
// chain; R2's NC=32 failure was strided scalar loads, fixed by R3 staging)
#define LNC 5
#define NC 32

// LDS row stride in shorts for 32-wide K tiles: 68 shorts = 34 dwords,
// 34 mod 32 = 2 -> <=2-way bank aliasing (free on CDNA4).
#define LSTR 68
// LDS row stride for full 128-K A tile: 136 shorts = 272 B (16B-aligned rows).
#define LSTRX 136

typedef __attribute__((ext_vector_type(8))) short bf16x8;
typedef __attribute__((ext_vector_type(4))) float f32x4;
typedef __attribute__((ext_vector_type(4))) unsigned short u16x4;

__device__ __forceinline__ float silu_f(float z) {
    return z * __builtin_amdgcn_rcpf(1.0f + __expf(-z));
}

__device__ __forceinline__ float softplus_f(float z) {
    return fmaxf(z, 0.0f) + __logf(1.0f + __expf(-fabsf(z)));
}

__device__ __forceinline__ short f2bf(float f) {
    union { float f; unsigned int u; } v; v.f = f;
    unsigned int r = v.u + 0x7FFF + ((v.u >> 16) & 1);   // round-nearest-even
    return (short)(r >> 16);
}

__device__ __forceinline__ float bf2f(unsigned short s) {
    union { float f; unsigned int u; } v;
    v.u = ((unsigned int)s) << 16;
    return v.f;
}

__device__ __forceinline__ bf16x8 pack8(float4 a, float4 b) {
    bf16x8 r;
    r[0] = f2bf(a.x); r[1] = f2bf(a.y); r[2] = f2bf(a.z); r[3] = f2bf(a.w);
    r[4] = f2bf(b.x); r[5] = f2bf(b.y); r[6] = f2bf(b.z); r[7] = f2bf(b.w);
    return r;
}

// ---------------------------------------------------------------------------
// Kernel 1 (R5 form, verified best): split-K up-projection, BK=32,
// double-buffered LDS + reg-prefetch, 1 barrier/step. 512 blocks;
// 128x64 tiles; fp32 partials to P0/P1.
// ---------------------------------------------------------------------------
__global__ __launch_bounds__(256) void gemm_up_splitk(
    const float* __restrict__ A,     // [M,1024]
    const float* __restrict__ W,     // [1024,256]
    float* __restrict__ P0,          // [M,256]
    float* __restrict__ P1)          // [M,256]
{
    __shared__ short Al[2][128 * LSTR];
    __shared__ short Bl[2][64 * LSTR];

    int lid = blockIdx.x;            // 0..511
    int xcd = lid & 7;
    int slot = lid >> 3;             // 0..63
    int bm = xcd * 8 + (slot >> 3);  // 0..63 (128-row tiles)
    int r3 = slot & 7;
    int bn = r3 & 3;
    int split = r3 >> 2;
    float* P = split ? P1 : P0;
    int k0 = split * 512;

    int tid = threadIdx.x;
    int w = tid >> 6, l = tid & 63;
    int lm = l & 15, q = l >> 4;
    int wm = w * 32;                 // wave covers rows wm..wm+31, all 64 cols

    f32x4 acc[2][4];
    #pragma unroll
    for (int i = 0; i < 2; i++)
        #pragma unroll
        for (int f = 0; f < 4; f++)
            acc[i][f] = (f32x4){0.f, 0.f, 0.f, 0.f};

    int ar = tid >> 1, ak = (tid & 1) * 16;   // A: 128 rows x 32 K, 16 fl/thread
    int bcol = tid & 63, bk = (tid >> 6) * 8;

    const float* Ag = A + (size_t)(bm * 128 + ar) * 1024 + k0 + ak;
    const float* Wg = W + (size_t)k0 * TWO_D + (size_t)bn * 64 + bcol;

    // preload step 0 into registers
    float4 a0 = *(const float4*)(Ag);
    float4 a1 = *(const float4*)(Ag + 4);
    float4 a2 = *(const float4*)(Ag + 8);
    float4 a3 = *(const float4*)(Ag + 12);
    float w0 = Wg[(size_t)(bk + 0) * TWO_D];
    float w1 = Wg[(size_t)(bk + 1) * TWO_D];
    float w2 = Wg[(size_t)(bk + 2) * TWO_D];
    float w3 = Wg[(size_t)(bk + 3) * TWO_D];
    float w4 = Wg[(size_t)(bk + 4) * TWO_D];
    float w5 = Wg[(size_t)(bk + 5) * TWO_D];
    float w6 = Wg[(size_t)(bk + 6) * TWO_D];
    float w7 = Wg[(size_t)(bk + 7) * TWO_D];

    int p = 0;
    for (int kt = 0; kt < 512; kt += 32) {
        // write LDS buf p from regs
        *(bf16x8*)&Al[p][ar * LSTR + ak]     = pack8(a0, a1);
        *(bf16x8*)&Al[p][ar * LSTR + ak + 8] = pack8(a2, a3);
        *(bf16x8*)&Bl[p][bcol * LSTR + bk] =
            pack8(make_float4(w0, w1, w2, w3), make_float4(w4, w5, w6, w7));

        // prefetch step kt+32 into regs (latency hidden under barrier+MFMA)
        if (kt + 32 < 512) {
            a0 = *(const float4*)(Ag + kt + 32);
            a1 = *(const float4*)(Ag + kt + 36);
            a2 = *(const float4*)(Ag + kt + 40);
            a3 = *(const float4*)(Ag + kt + 44);
            w0 = Wg[(size_t)(kt + 32 + bk + 0) * TWO_D];
            w1 = Wg[(size_t)(kt + 32 + bk + 1) * TWO_D];
            w2 = Wg[(size_t)(kt + 32 + bk + 2) * TWO_D];
            w3 = Wg[(size_t)(kt + 32 + bk + 3) * TWO_D];
            w4 = Wg[(size_t)(kt + 32 + bk + 4) * TWO_D];
            w5 = Wg[(size_t)(kt + 32 + bk + 5) * TWO_D];
            w6 = Wg[(size_t)(kt + 32 + bk + 6) * TWO_D];
            w7 = Wg[(size_t)(kt + 32 + bk + 7) * TWO_D];
        }

        __syncthreads();   // single barrier per step (dbuf makes 2nd redundant)

        bf16x8 af0 = *(bf16x8*)&Al[p][(wm + lm) * LSTR + q * 8];
        bf16x8 af1 = *(bf16x8*)&Al[p][(wm + 16 + lm) * LSTR + q * 8];
        bf16x8 bfr[4];
        #pragma unroll
        for (int f = 0; f < 4; f++)
            bfr[f] = *(bf16x8*)&Bl[p][(f * 16 + lm) * LSTR + q * 8];

        #pragma unroll
        for (int f = 0; f < 4; f++) {
            acc[0][f] = __builtin_amdgcn_mfma_f32_16x16x32_bf16(af0, bfr[f], acc[0][f], 0, 0, 0);
            acc[1][f] = __builtin_amdgcn_mfma_f32_16x16x32_bf16(af1, bfr[f], acc[1][f], 0, 0, 0);
        }

        p ^= 1;
    }

    #pragma unroll
    for (int i = 0; i < 2; i++)
        #pragma unroll
        for (int f = 0; f < 4; f++)
            #pragma unroll
            for (int e = 0; e < 4; e++) {
                int row = bm * 128 + wm + i * 16 + q * 4 + e;
                int col = bn * 64 + f * 16 + lm;
                P[(size_t)row * TWO_D + col] = acc[i][f][e];
            }
}

// ---------------------------------------------------------------------------
// Kernel 2 (R5 form): fused (split-K reduce + bias) + causal conv K=3 + SiLU
// + gate + delta/B/C MFMA projection (pipelined Bl, 1 barrier/step).
// 512 blocks = 8 XCD x 16 bm x 4 bn.
// ---------------------------------------------------------------------------
__global__ __launch_bounds__(256) void convproj_mfma(
    const float* __restrict__ P0,      // [M,256]
    const float* __restrict__ P1,      // [M,256]
    const float* __restrict__ b_up,    // [256]
    const float* __restrict__ conv_w,  // [D,3]
    const float* __restrict__ conv_b,  // [D]
    const float* __restrict__ W_delta, const float* __restrict__ b_delta,
    const float* __restrict__ W_B,     const float* __restrict__ b_B,
    const float* __restrict__ W_C,     const float* __restrict__ b_C,
    unsigned short* __restrict__ x,    // [M,128] bf16 (for scan)
    float* __restrict__ u,             // [M,256] (right half written)
    unsigned short* __restrict__ delta,// [M,128] bf16
    unsigned short* __restrict__ Bm,   // [M,64] bf16
    unsigned short* __restrict__ Cm)   // [M,64] bf16
{
    __shared__ float uu[66 * 128];     // rows -2..63, conv cols
    __shared__ short Xl[64 * LSTRX];   // bf16 A operand, full K=128
    __shared__ short Bl[2][64 * LSTR];

    int lid = blockIdx.x;
    int xcd = lid & 7;
    int slot = lid >> 3;
    int bm = xcd * 16 + (slot >> 2);
    int bn = slot & 3;
    int tid = threadIdx.x;

    bool seq_start = (bm & 31) == 0;   // tile starts at t==0 of a sequence

    // ---- stage uu = P0+P1+b_up for rows bm*64-2 .. bm*64+63, cols 0..127 ----
    #pragma unroll
    for (int i = 0; i < 9; i++) {
        int fi = tid + i * 256;        // float4 index, 2112 total
        if (fi < 2112) {
            int row = fi >> 5;         // 0..65
            int c4 = (fi & 31) * 4;    // 0..124
            int gr = bm * 64 + row - 2;
            float4 v;
            if (seq_start && row < 2) {
                v = make_float4(0.f, 0.f, 0.f, 0.f);
            } else {
                size_t gi = (size_t)gr * TWO_D + c4;
                float4 p0 = *(const float4*)&P0[gi];
                float4 p1 = *(const float4*)&P1[gi];
                float4 bb = *(const float4*)&b_up[c4];
                v = make_float4(p0.x + p1.x + bb.x, p0.y + p1.y + bb.y,
                                p0.z + p1.z + bb.z, p0.w + p1.w + bb.w);
            }
            *(float4*)&uu[fi * 4] = v;
        }
    }

    // ---- gate half (bn==1 writes u[:,128:256]) ----
    if (bn == 1) {
        #pragma unroll
        for (int i = 0; i < 8; i++) {
            int fi = tid + i * 256;    // 2048 float4s
            int row = fi >> 5;
            int c4 = (fi & 31) * 4 + 128;
            int gr = bm * 64 + row;
            size_t gi = (size_t)gr * TWO_D + c4;
            float4 p0 = *(const float4*)&P0[gi];
            float4 p1 = *(const float4*)&P1[gi];
            float4 bb = *(const float4*)&b_up[c4];
            *(float4*)&u[gi] = make_float4(p0.x + p1.x + bb.x, p0.y + p1.y + bb.y,
                                           p0.z + p1.z + bb.z, p0.w + p1.w + bb.w);
        }
    }
    __syncthreads();

    // ---- conv + silu -> Xl (bf16) and (bn==0) x global (bf16) ----
    #pragma unroll
    for (int i = 0; i < 8; i++) {
        int fi = tid + i * 256;        // 2048 float4 outputs
        int row = fi >> 5;             // 0..63
        int c4 = (fi & 31) * 4;
        float4 v2 = *(const float4*)&uu[(row + 2) * 128 + c4];
        float4 v1 = *(const float4*)&uu[(row + 1) * 128 + c4];
        float4 v0 = *(const float4*)&uu[(row + 0) * 128 + c4];
        float4 z;
        {
            float w0 = conv_w[(c4 + 0) * 3 + 0], w1 = conv_w[(c4 + 0) * 3 + 1], w2 = conv_w[(c4 + 0) * 3 + 2];
            z.x = silu_f(fmaf(w0, v0.x, fmaf(w1, v1.x, fmaf(w2, v2.x, conv_b[c4 + 0]))));
        }
        {
            float w0 = conv_w[(c4 + 1) * 3 + 0], w1 = conv_w[(c4 + 1) * 3 + 1], w2 = conv_w[(c4 + 1) * 3 + 2];
            z.y = silu_f(fmaf(w0, v0.y, fmaf(w1, v1.y, fmaf(w2, v2.y, conv_b[c4 + 1]))));
        }
        {
            float w0 = conv_w[(c4 + 2) * 3 + 0], w1 = conv_w[(c4 + 2) * 3 + 1], w2 = conv_w[(c4 + 2) * 3 + 2];
            z.z = silu_f(fmaf(w0, v0.z, fmaf(w1, v1.z, fmaf(w2, v2.z, conv_b[c4 + 2]))));
        }
        {
            float w0 = conv_w[(c4 + 3) * 3 + 0], w1 = conv_w[(c4 + 3) * 3 + 1], w2 = conv_w[(c4 + 3) * 3 + 2];
            z.w = silu_f(fmaf(w0, v0.w, fmaf(w1, v1.w, fmaf(w2, v2.w, conv_b[c4 + 3]))));
        }
        short4 zb;
        zb.x = f2bf(z.x); zb.y = f2bf(z.y); zb.z = f2bf(z.z); zb.w = f2bf(z.w);
        *(short4*)&Xl[row * LSTRX + c4] = zb;
        if (bn == 0) {
            int gr = bm * 64 + row;
            *(short4*)&x[(size_t)gr * D_ + c4] = zb;
        }
    }

    // ---- weight select ----
    const float* Wsel; const float* bsel; int wstride;
    if (bn < 2)       { Wsel = W_delta + bn * 64; bsel = b_delta + bn * 64; wstride = 128; }
    else if (bn == 2) { Wsel = W_B;               bsel = b_B;               wstride = 64;  }
    else              { Wsel = W_C;               bsel = b_C;               wstride = 64;  }

    int w = tid >> 6, l = tid & 63;
    int lm = l & 15, q = l >> 4;
    int wm = (w & 1) * 32, wn = (w >> 1) * 32;

    f32x4 acc00 = {0,0,0,0}, acc01 = {0,0,0,0}, acc10 = {0,0,0,0}, acc11 = {0,0,0,0};

    int bcol = tid & 63, bk = (tid >> 6) * 8;
    const float* Wg = Wsel + bcol;

    // preload step 0 W into regs (no pre-loop barrier needed: first in-loop
    // barrier covers the Xl writes above)
    float w0 = Wg[(size_t)(bk + 0) * wstride];
    float w1 = Wg[(size_t)(bk + 1) * wstride];
    float w2 = Wg[(size_t)(bk + 2) * wstride];
    float w3 = Wg[(size_t)(bk + 3) * wstride];
    float w4 = Wg[(size_t)(bk + 4) * wstride];
    float w5 = Wg[(size_t)(bk + 5) * wstride];
    float w6 = Wg[(size_t)(bk + 6) * wstride];
    float w7 = Wg[(size_t)(bk + 7) * wstride];

    int p = 0;
    for (int kt = 0; kt < 128; kt += 32) {
        *(bf16x8*)&Bl[p][bcol * LSTR + bk] =
            pack8(make_float4(w0, w1, w2, w3), make_float4(w4, w5, w6, w7));

        if (kt + 32 < 128) {
            w0 = Wg[(size_t)(kt + 32 + bk + 0) * wstride];
            w1 = Wg[(size_t)(kt + 32 + bk + 1) * wstride];
            w2 = Wg[(size_t)(kt + 32 + bk + 2) * wstride];
            w3 = Wg[(size_t)(kt + 32 + bk + 3) * wstride];
            w4 = Wg[(size_t)(kt + 32 + bk + 4) * wstride];
            w5 = Wg[(size_t)(kt + 32 + bk + 5) * wstride];
            w6 = Wg[(size_t)(kt + 32 + bk + 6) * wstride];
            w7 = Wg[(size_t)(kt + 32 + bk + 7) * wstride];
        }

        __syncthreads();

        bf16x8 af0 = *(bf16x8*)&Xl[(wm + lm) * LSTRX + kt + q * 8];
        bf16x8 af1 = *(bf16x8*)&Xl[(wm + 16 + lm) * LSTRX + kt + q * 8];
        bf16x8 bf0 = *(bf16x8*)&Bl[p][(wn + lm) * LSTR + q * 8];
        bf16x8 bf1 = *(bf16x8*)&Bl[p][(wn + 16 + lm) * LSTR + q * 8];

        acc00 = __builtin_amdgcn_mfma_f32_16x16x32_bf16(af0, bf0, acc00, 0, 0, 0);
        acc01 = __builtin_amdgcn_mfma_f32_16x16x32_bf16(af0, bf1, acc01, 0, 0, 0);
        acc10 = __builtin_amdgcn_mfma_f32_16x16x32_bf16(af1, bf0, acc10, 0, 0, 0);
        acc11 = __builtin_amdgcn_mfma_f32_16x16x32_bf16(af1, bf1, acc11, 0, 0, 0);

        p ^= 1;
    }

    #pragma unroll
    for (int i = 0; i < 4; i++) {
        int r0 = bm * 64 + wm + q * 4 + i;
        int r1 = r0 + 16;
        int c0 = wn + lm;
        int c1 = c0 + 16;
        float v00 = acc00[i] + bsel[c0];
        float v01 = acc01[i] + bsel[c1];
        float v10 = acc10[i] + bsel[c0];
        float v11 = acc11[i] + bsel[c1];
        if (bn < 2) {
            int cc0 = bn * 64 + c0, cc1 = bn * 64 + c1;
            delta[(size_t)r0 * D_ + cc0] = (unsigned short)f2bf(softplus_f(v00));
            delta[(size_t)r0 * D_ + cc1] = (unsigned short)f2bf(softplus_f(v01));
            delta[(size_t)r1 * D_ + cc0] = (unsigned short)f2bf(softplus_f(v10));
            delta[(size_t)r1 * D_ + cc1] = (unsigned short)f2bf(softplus_f(v11));
        } else if (bn == 2) {
            Bm[(size_t)r0 * N_ + c0] = (unsigned short)f2bf(v00);
            Bm[(size_t)r0 * N_ + c1] = (unsigned short)f2bf(v01);
            Bm[(size_t)r1 * N_ + c0] = (unsigned short)f2bf(v10);
            Bm[(size_t)r1 * N_ + c1] = (unsigned short)f2bf(v11);
        } else {
            Cm[(size_t)r0 * N_ + c0] = (unsigned short)f2bf(v00);
            Cm[(size_t)r0 * N_ + c1] = (unsigned short)f2bf(v01);
            Cm[(size_t)r1 * N_ + c0] = (unsigned short)f2bf(v10);
            Cm[(size_t)r1 * N_ + c1] = (unsigned short)f2bf(v11);
        }
    }
}

// ---------------------------------------------------------------------------
// Kernel 3a (R9): summary pass, NC=32 / TC=64. LDS-staged chunk tiles
// (R3 scheme, stage loops x2). Grid 1024 = 4 b x 8 dqg x 32 c.
// ---------------------------------------------------------------------------
__global__ __launch_bounds__(256) void scan_sumA(
    const unsigned short* __restrict__ delta,   // [M,D] bf16
    const unsigned short* __restrict__ x,       // [M,D] bf16
    const unsigned short* __restrict__ Bm,      // [M,N] bf16
    const float* __restrict__ A_log,            // [D,N]
    float* __restrict__ ch_aprod,               // [B,D,NC,N]
    float* __restrict__ ch_h)                   // [B,D,NC,N]
{
    constexpr int TCt = L_ >> LNC;              // 64
    __shared__ unsigned short ld_d[TCt * 16];   // 2 KB
    __shared__ unsigned short ld_x[TCt * 16];   // 2 KB
    __shared__ unsigned short ld_b[TCt * 64];   // 8 KB

    int blk = blockIdx.x;              // 1024 = 4 b x 8 dqg x 32 c
    int c = blk & (NC - 1);
    int dqg = (blk >> LNC) & 7;
    int b = blk >> (LNC + 3);
    int tid = threadIdx.x;
    int wv = tid >> 6;
    int l = tid & 63;
    int g = l >> 4, j = l & 15;
    int d0 = dqg * 16;
    int d = d0 + wv * 4 + g;
    int dloc = wv * 4 + g;

    size_t row0 = (size_t)b * L_ + c * TCt;

    // ---- stage: delta/x (threads 0-127 / 128-255, 2 rows-batches each) ----
    #pragma unroll
    for (int it = 0; it < 2; it++) {
        int t = ((tid & 127) >> 2) + it * 32;  // 0..63
        int c4 = (tid & 3) * 4;
        const unsigned short* src = (tid < 128) ? delta : x;
        unsigned short* dst = (tid < 128) ? ld_d : ld_x;
        *(u16x4*)&dst[t * 16 + c4] = *(const u16x4*)&src[(row0 + t) * D_ + d0 + c4];
    }
    #pragma unroll
    for (int it = 0; it < 2; it++) {
        int t = (tid >> 3) + it * 32;          // 0..63
        int c8 = (tid & 7) * 8;
        *(bf16x8*)&ld_b[t * 64 + c8] = *(const bf16x8*)&Bm[(row0 + t) * N_ + c8];
    }

    const float LOG2E = 1.44269504089f;
    float4 Ar = *(const float4*)&A_log[d * N_ + j * 4];
    float Ai0 = -__expf(Ar.x) * LOG2E;
    float Ai1 = -__expf(Ar.y) * LOG2E;
    float Ai2 = -__expf(Ar.z) * LOG2E;
    float Ai3 = -__expf(Ar.w) * LOG2E;

    __syncthreads();

    float h0 = 0, h1 = 0, h2 = 0, h3 = 0;
    float S = 0;

    #pragma unroll 8
    for (int t = 0; t < TCt; t++) {
        float dl = bf2f(ld_d[t * 16 + dloc]);
        float xv = bf2f(ld_x[t * 16 + dloc]);
        u16x4 bv = *(const u16x4*)&ld_b[t * 64 + j * 4];
        float e0 = exp2f(dl * Ai0);
        float e1 = exp2f(dl * Ai1);
        float e2 = exp2f(dl * Ai2);
        float e3 = exp2f(dl * Ai3);
        float dbx = dl * xv;
        h0 = fmaf(e0, h0, dbx * bf2f(bv[0]));
        h1 = fmaf(e1, h1, dbx * bf2f(bv[1]));
        h2 = fmaf(e2, h2, dbx * bf2f(bv[2]));
        h3 = fmaf(e3, h3, dbx * bf2f(bv[3]));
        S += dl;
    }

    size_t ci = (((size_t)b * D_ + d) * NC + c) * N_ + j * 4;
    *(float4*)&ch_aprod[ci] = make_float4(exp2f(Ai0 * S), exp2f(Ai1 * S),
                                          exp2f(Ai2 * S), exp2f(Ai3 * S));
    *(float4*)&ch_h[ci]     = make_float4(h0, h1, h2, h3);
}

// ---------------------------------------------------------------------------
// Kernel 3b: serial prefix over NC=32 chunk summaries, per (b,d,n).
// One wave per (b,d); lanes = n (coalesced 256B rows).
// ---------------------------------------------------------------------------
__global__ __launch_bounds__(64) void scan_prefix(
    float* __restrict__ aprod_hin,     // in: chunk aprod; out: hin
    const float* __restrict__ ch_h)
{
    int idx = blockIdx.x * 64 + threadIdx.x;    // B*D*N = 32768 exact
    int n = idx & 63;
    int rest = idx >> 6;
    size_t base = (size_t)rest * NC * N_ + n;
    float h = 0.0f;
    #pragma unroll 8
    for (int c = 0; c < NC; c++) {
        size_t o = base + (size_t)c * N_;
        float a  = aprod_hin[o];
        float hh = ch_h[o];
        aprod_hin[o] = h;
        h = fmaf(a, h, hh);
    }
}

// ---------------------------------------------------------------------------
// Kernel 3c (R9): output pass, NC=32 / TC=64. LDS-staged tiles; SiLU gate
// applied once; bf16 `gated` written coalesced. Grid 1024.
// ---------------------------------------------------------------------------
__global__ __launch_bounds__(256) void scan_outB(
    const unsigned short* __restrict__ delta,   // [M,D] bf16
    const unsigned short* __restrict__ x,       // [M,D] bf16
    const unsigned short* __restrict__ Bm,      // [M,N] bf16
    const unsigned short* __restrict__ Cm,      // [M,N] bf16
    const float* __restrict__ A_log,            // [D,N]
    const float* __restrict__ D_skip,           // [D]
    const float* __restrict__ hin,              // [B,D,NC,N]
    const float* __restrict__ u,                // [M,256] right-half gates
    short* __restrict__ gated)                  // [M,128] bf16: y * silu(u_r)
{
    constexpr int TCt = L_ >> LNC;              // 64
    __shared__ unsigned short ld_d[TCt * 16];   // 2 KB
    __shared__ unsigned short ld_x[TCt * 16];   // 2 KB
    __shared__ unsigned short ld_b[TCt * 64];   // 8 KB
    __shared__ unsigned short ld_c[TCt * 64];   // 8 KB
    __shared__ float yl[TCt * 16];              // 4 KB

    int blk = blockIdx.x;              // 1024 = 4 b x 8 dqg x 32 c
    int c = blk & (NC - 1);
    int dqg = (blk >> LNC) & 7;
    int b = blk >> (LNC + 3);
    int tid = threadIdx.x;
    int wv = tid >> 6;
    int l = tid & 63;
    int g = l >> 4, j = l & 15;
    int d0 = dqg * 16;
    int d = d0 + wv * 4 + g;
    int dloc = wv * 4 + g;

    size_t row0 = (size_t)b * L_ + c * TCt;

    // ---- stage ----
    #pragma unroll
    for (int it = 0; it < 2; it++) {
        int t = ((tid & 127) >> 2) + it * 32;
        int c4 = (tid & 3) * 4;
        const unsigned short* src = (tid < 128) ? delta : x;
        unsigned short* dst = (tid < 128) ? ld_d : ld_x;
        *(u16x4*)&dst[t * 16 + c4] = *(const u16x4*)&src[(row0 + t) * D_ + d0 + c4];
    }
    #pragma unroll
    for (int it = 0; it < 2; it++) {
        int t = (tid >> 3) + it * 32;
        int c8 = (tid & 7) * 8;
        *(bf16x8*)&ld_b[t * 64 + c8] = *(const bf16x8*)&Bm[(row0 + t) * N_ + c8];
        *(bf16x8*)&ld_c[t * 64 + c8] = *(const bf16x8*)&Cm[(row0 + t) * N_ + c8];
    }

    const float LOG2E = 1.44269504089f;
    float4 Ar = *(const float4*)&A_log[d * N_ + j * 4];
    float Ai0 = -__expf(Ar.x) * LOG2E;
    float Ai1 = -__expf(Ar.y) * LOG2E;
    float Ai2 = -__expf(Ar.z) * LOG2E;
    float Ai3 = -__expf(Ar.w) * LOG2E;
    float dsk = D_skip[d];

    float4 hv = *(const float4*)&hin[(((size_t)b * D_ + d) * NC + c) * N_ + j * 4];
    float h0 = hv.x, h1 = hv.y, h2 = hv.z, h3 = hv.w;

    __syncthreads();

    #pragma unroll 8
    for (int t = 0; t < TCt; t++) {
        float dl = bf2f(ld_d[t * 16 + dloc]);
        float xv = bf2f(ld_x[t * 16 + dloc]);
        u16x4 bv = *(const u16x4*)&ld_b[t * 64 + j * 4];
        u16x4 cv = *(const u16x4*)&ld_c[t * 64 + j * 4];
        float e0 = exp2f(dl * Ai0);
        float e1 = exp2f(dl * Ai1);
        float e2 = exp2f(dl * Ai2);
        float e3 = exp2f(dl * Ai3);
        float dbx = dl * xv;
        h0 = fmaf(e0, h0, dbx * bf2f(bv[0]));
        h1 = fmaf(e1, h1, dbx * bf2f(bv[1]));
        h2 = fmaf(e2, h2, dbx * bf2f(bv[2]));
        h3 = fmaf(e3, h3, dbx * bf2f(bv[3]));
        float p = fmaf(h0, bf2f(cv[0]), fmaf(h1, bf2f(cv[1]),
                  fmaf(h2, bf2f(cv[2]), h3 * bf2f(cv[3]))));
        p += __shfl_xor(p, 1, 64);
        p += __shfl_xor(p, 2, 64);
        p += __shfl_xor(p, 4, 64);
        p += __shfl_xor(p, 8, 64);
        if (j == 0) yl[t * 16 + dloc] = fmaf(dsk, xv, p);
    }

    __syncthreads();

    // gate + bf16 pack + coalesced write: 64 t-rows x 16 d = 256 float4s
    {
        int t = tid >> 2;              // 0..63
        int c4 = (tid & 3) * 4;        // 0,4,8,12
        size_t row = row0 + t;
        float4 yv = *(float4*)&yl[t * 16 + c4];
        float4 gv = *(const float4*)&u[row * TWO_D + 128 + d0 + c4];
        short4 o;
        o.x = f2bf(yv.x * silu_f(gv.x));
        o.y = f2bf(yv.y * silu_f(gv.y));
        o.z = f2bf(yv.z * silu_f(gv.z));
        o.w = f2bf(yv.w * silu_f(gv.w));
        *(short4*)&gated[row * D_ + d0 + c4] = o;
    }
}

// ---------------------------------------------------------------------------
// Kernel 4 (R5 form): out = gated @ W_down + b_down. Pipelined dbuf LDS,
// reg prefetch, one barrier per step.
// ---------------------------------------------------------------------------
__global__ __launch_bounds__(256) void gemm_down_mfma(
    const short* __restrict__ gated, // [M,128] bf16
    const float* __restrict__ W,     // [128,1024]
    const float* __restrict__ bias,  // [1024]
    float* __restrict__ out)         // [M,1024]
{
    __shared__ short Al[2][64 * LSTR];
    __shared__ short Bl[2][64 * LSTR];

    int lid = blockIdx.x;            // 0..2047
    int xcd = lid & 7;
    int slot = lid >> 3;
    int bm = xcd * 16 + (slot >> 4);
    int bn = slot & 15;

    int tid = threadIdx.x;
    int w = tid >> 6, l = tid & 63;
    int lm = l & 15, q = l >> 4;
    int wm = (w & 1) * 32, wn = (w >> 1) * 32;

    f32x4 acc00 = {0,0,0,0}, acc01 = {0,0,0,0}, acc10 = {0,0,0,0}, acc11 = {0,0,0,0};

    int ar = tid >> 2, ak = (tid & 3) * 8;
    int bcol = tid & 63, bk = (tid >> 6) * 8;

    const short* Gg = gated + (size_t)(bm * 64 + ar) * D_ + ak;
    const float* Wg = W + (size_t)bn * 64 + bcol;

    // preload step 0
    bf16x8 av = *(const bf16x8*)(Gg);
    float w0 = Wg[(size_t)(bk + 0) * R_];
    float w1 = Wg[(size_t)(bk + 1) * R_];
    float w2 = Wg[(size_t)(bk + 2) * R_];
    float w3 = Wg[(size_t)(bk + 3) * R_];
    float w4 = Wg[(size_t)(bk + 4) * R_];
    float w5 = Wg[(size_t)(bk + 5) * R_];
    float w6 = Wg[(size_t)(bk + 6) * R_];
    float w7 = Wg[(size_t)(bk + 7) * R_];

    int p = 0;
    for (int kt = 0; kt < 128; kt += 32) {
        *(bf16x8*)&Al[p][ar * LSTR + ak] = av;
        *(bf16x8*)&Bl[p][bcol * LSTR + bk] =
            pack8(make_float4(w0, w1, w2, w3), make_float4(w4, w5, w6, w7));

        if (kt + 32 < 128) {
            av = *(const bf16x8*)(Gg + kt + 32);
            w0 = Wg[(size_t)(kt + 32 + bk + 0) * R_];
            w1 = Wg[(size_t)(kt + 32 + bk + 1) * R_];
            w2 = Wg[(size_t)(kt + 32 + bk + 2) * R_];
            w3 = Wg[(size_t)(kt + 32 + bk + 3) * R_];
            w4 = Wg[(size_t)(kt + 32 + bk + 4) * R_];
            w5 = Wg[(size_t)(kt + 32 + bk + 5) * R_];
            w6 = Wg[(size_t)(kt + 32 + bk + 6) * R_];
            w7 = Wg[(size_t)(kt + 32 + bk + 7) * R_];
        }

        __syncthreads();

        bf16x8 af0 = *(bf16x8*)&Al[p][(wm + lm) * LSTR + q * 8];
        bf16x8 af1 = *(bf16x8*)&Al[p][(wm + 16 + lm) * LSTR + q * 8];
        bf16x8 bf0 = *(bf16x8*)&Bl[p][(wn + lm) * LSTR + q * 8];
        bf16x8 bf1 = *(bf16x8*)&Bl[p][(wn + 16 + lm) * LSTR + q * 8];

        acc00 = __builtin_amdgcn_mfma_f32_16x16x32_bf16(af0, bf0, acc00, 0, 0, 0);
        acc01 = __builtin_amdgcn_mfma_f32_16x16x32_bf16(af0, bf1, acc01, 0, 0, 0);
        acc10 = __builtin_amdgcn_mfma_f32_16x16x32_bf16(af1, bf0, acc10, 0, 0, 0);
        acc11 = __builtin_amdgcn_mfma_f32_16x16x32_bf16(af1, bf1, acc11, 0, 0, 0);

        p ^= 1;
    }

    #pragma unroll
    for (int i = 0; i < 4; i++) {
        int r0 = bm * 64 + wm + q * 4 + i;
        int r1 = r0 + 16;
        int c0 = bn * 64 + wn + lm;
        int c1 = c0 + 16;
        out[(size_t)r0 * R_ + c0] = acc00[i] + bias[c0];
        out[(size_t)r0 * R_ + c1] = acc01[i] + bias[c1];
        out[(size_t)r1 * R_ + c0] = acc10[i] + bias[c0];
        out[(size_t)r1 * R_ + c1] = acc11[i] + bias[c1];
    }
}

// ---------------------------------------------------------------------------
extern "C" void kernel_launch(void* const* d_in, const int* in_sizes, int n_in,
                              void* d_out, int out_size, void* d_ws, size_t ws_size,
                              hipStream_t stream)
{
    const float* up_x    = (const float*)d_in[0];
    const float* W_up    = (const float*)d_in[1];
    const float* b_up    = (const float*)d_in[2];
    const float* conv_w  = (const float*)d_in[3];
    const float* conv_b  = (const float*)d_in[4];
    const float* W_delta = (const float*)d_in[5];
    const float* b_delta = (const float*)d_in[6];
    const float* W_B     = (const float*)d_in[7];
    const float* b_B     = (const float*)d_in[8];
    const float* W_C     = (const float*)d_in[9];
    const float* b_C     = (const float*)d_in[10];
    const float* A_log   = (const float*)d_in[11];
    const float* D_skip  = (const float*)d_in[12];
    const float* W_down  = (const float*)d_in[13];
    const float* b_down  = (const float*)d_in[14];

    float* out = (float*)d_out;
    float* ws  = (float*)d_ws;

    // workspace layout (all regions DEDICATED, 16B-aligned):
    float* u = ws;                                       // fp32 [M,256]
    unsigned short* x16     = (unsigned short*)(u + (size_t)M_ * TWO_D);
    unsigned short* delta16 = x16     + (size_t)M_ * D_;
    unsigned short* Bm16    = delta16 + (size_t)M_ * D_;
    unsigned short* Cm16    = Bm16    + (size_t)M_ * N_;
    unsigned short* gated   = Cm16    + (size_t)M_ * N_;
    float* ch_aprod = (float*)(gated + (size_t)M_ * D_); // 4 MB (NC=32)
    float* ch_h     = ch_aprod + (size_t)B_ * D_ * NC * N_;
    float* P0       = ch_h     + (size_t)B_ * D_ * NC * N_;
    float* P1       = P0       + (size_t)M_ * TWO_D;

    // 1. split-K up-projection (R5 pipelined form)
    gemm_up_splitk<<<512, 256, 0, stream>>>(up_x, W_up, P0, P1);

    // 2. fused reduce+bias+conv+silu+gate+delta/B/C projection (R5 form)
    convproj_mfma<<<512, 256, 0, stream>>>(
        P0, P1, b_up, conv_w, conv_b,
        W_delta, b_delta, W_B, b_B, W_C, b_C,
        x16, u, delta16, Bm16, Cm16);

    // 3. chunked scan (NC=32): summaries -> prefix -> output
    scan_sumA<<<B_ * 8 * NC, 256, 0, stream>>>(
        delta16, x16, Bm16, A_log, ch_aprod, ch_h);
    scan_prefix<<<(B_ * D_ * N_) / 64, 64, 0, stream>>>(
        ch_aprod, ch_h);
    scan_outB<<<B_ * 8 * NC, 256, 0, stream>>>(
        delta16, x16, Bm16, Cm16, A_log, D_skip, ch_aprod, u, (short*)gated);

    // 4. down-projection GEMM (R5 pipelined form)
    gemm_down_mfma<<<2048, 256, 0, stream>>>(
        (const short*)gated, W_down, b_down, out);
}

// Round 10
// 193.655 us; speedup vs baseline: 1.0393x; 1.0393x over previous
//
#include <hip/hip_runtime.h>
#include <math.h>

// Problem constants (from reference)
#define B_ 4
#define L_ 2048
#define R_ 1024
#define D_ 128      // ssm input dim
#define N_ 64       // state size
#define TWO_D 256   // 2*D
#define M_ (B_*L_)  // 8192 rows

// scan chunking: NC=64 chunks of TC=32 (confirmed optimal: NC=32 falsified
// twice, R2 unstaged and R9 staged — scans are latency/TLP-bound)
#define LNC 6
#define NC 64

// LDS row stride in shorts for 32-wide K tiles: 68 shorts = 34 dwords,
// 34 mod 32 = 2 -> <=2-way bank aliasing (free on CDNA4).
#define LSTR 68
// LDS row stride for full 128-K A tile: 136 shorts = 272 B (16B-aligned rows).
#define LSTRX 136

typedef __attribute__((ext_vector_type(8))) short bf16x8;
typedef __attribute__((ext_vector_type(4))) float f32x4;
typedef __attribute__((ext_vector_type(4))) unsigned short u16x4;

__device__ __forceinline__ float silu_f(float z) {
    return z * __builtin_amdgcn_rcpf(1.0f + __expf(-z));
}

__device__ __forceinline__ float softplus_f(float z) {
    return fmaxf(z, 0.0f) + __logf(1.0f + __expf(-fabsf(z)));
}

__device__ __forceinline__ short f2bf(float f) {
    union { float f; unsigned int u; } v; v.f = f;
    unsigned int r = v.u + 0x7FFF + ((v.u >> 16) & 1);   // round-nearest-even
    return (short)(r >> 16);
}

__device__ __forceinline__ float bf2f(unsigned short s) {
    union { float f; unsigned int u; } v;
    v.u = ((unsigned int)s) << 16;
    return v.f;
}

__device__ __forceinline__ bf16x8 pack8(float4 a, float4 b) {
    bf16x8 r;
    r[0] = f2bf(a.x); r[1] = f2bf(a.y); r[2] = f2bf(a.z); r[3] = f2bf(a.w);
    r[4] = f2bf(b.x); r[5] = f2bf(b.y); r[6] = f2bf(b.z); r[7] = f2bf(b.w);
    return r;
}

// ---------------------------------------------------------------------------
// Kernel 1 (R5 form, verified best): split-K up-projection, BK=32,
// double-buffered LDS + reg-prefetch, 1 barrier/step. 512 blocks;
// 128x64 tiles; fp32 partials to P0/P1.
// Falsified alternatives: full-K (R6/R7, +4.5..6.3us), BK=64 (R8, +2.4us),
// direct-global B-fragments (R4, +14us).
// ---------------------------------------------------------------------------
__global__ __launch_bounds__(256) void gemm_up_splitk(
    const float* __restrict__ A,     // [M,1024]
    const float* __restrict__ W,     // [1024,256]
    float* __restrict__ P0,          // [M,256]
    float* __restrict__ P1)          // [M,256]
{
    __shared__ short Al[2][128 * LSTR];
    __shared__ short Bl[2][64 * LSTR];

    int lid = blockIdx.x;            // 0..511
    int xcd = lid & 7;
    int slot = lid >> 3;             // 0..63
    int bm = xcd * 8 + (slot >> 3);  // 0..63 (128-row tiles)
    int r3 = slot & 7;
    int bn = r3 & 3;
    int split = r3 >> 2;
    float* P = split ? P1 : P0;
    int k0 = split * 512;

    int tid = threadIdx.x;
    int w = tid >> 6, l = tid & 63;
    int lm = l & 15, q = l >> 4;
    int wm = w * 32;                 // wave covers rows wm..wm+31, all 64 cols

    f32x4 acc[2][4];
    #pragma unroll
    for (int i = 0; i < 2; i++)
        #pragma unroll
        for (int f = 0; f < 4; f++)
            acc[i][f] = (f32x4){0.f, 0.f, 0.f, 0.f};

    int ar = tid >> 1, ak = (tid & 1) * 16;   // A: 128 rows x 32 K, 16 fl/thread
    int bcol = tid & 63, bk = (tid >> 6) * 8;

    const float* Ag = A + (size_t)(bm * 128 + ar) * 1024 + k0 + ak;
    const float* Wg = W + (size_t)k0 * TWO_D + (size_t)bn * 64 + bcol;

    // preload step 0 into registers
    float4 a0 = *(const float4*)(Ag);
    float4 a1 = *(const float4*)(Ag + 4);
    float4 a2 = *(const float4*)(Ag + 8);
    float4 a3 = *(const float4*)(Ag + 12);
    float w0 = Wg[(size_t)(bk + 0) * TWO_D];
    float w1 = Wg[(size_t)(bk + 1) * TWO_D];
    float w2 = Wg[(size_t)(bk + 2) * TWO_D];
    float w3 = Wg[(size_t)(bk + 3) * TWO_D];
    float w4 = Wg[(size_t)(bk + 4) * TWO_D];
    float w5 = Wg[(size_t)(bk + 5) * TWO_D];
    float w6 = Wg[(size_t)(bk + 6) * TWO_D];
    float w7 = Wg[(size_t)(bk + 7) * TWO_D];

    int p = 0;
    for (int kt = 0; kt < 512; kt += 32) {
        // write LDS buf p from regs
        *(bf16x8*)&Al[p][ar * LSTR + ak]     = pack8(a0, a1);
        *(bf16x8*)&Al[p][ar * LSTR + ak + 8] = pack8(a2, a3);
        *(bf16x8*)&Bl[p][bcol * LSTR + bk] =
            pack8(make_float4(w0, w1, w2, w3), make_float4(w4, w5, w6, w7));

        // prefetch step kt+32 into regs (latency hidden under barrier+MFMA)
        if (kt + 32 < 512) {
            a0 = *(const float4*)(Ag + kt + 32);
            a1 = *(const float4*)(Ag + kt + 36);
            a2 = *(const float4*)(Ag + kt + 40);
            a3 = *(const float4*)(Ag + kt + 44);
            w0 = Wg[(size_t)(kt + 32 + bk + 0) * TWO_D];
            w1 = Wg[(size_t)(kt + 32 + bk + 1) * TWO_D];
            w2 = Wg[(size_t)(kt + 32 + bk + 2) * TWO_D];
            w3 = Wg[(size_t)(kt + 32 + bk + 3) * TWO_D];
            w4 = Wg[(size_t)(kt + 32 + bk + 4) * TWO_D];
            w5 = Wg[(size_t)(kt + 32 + bk + 5) * TWO_D];
            w6 = Wg[(size_t)(kt + 32 + bk + 6) * TWO_D];
            w7 = Wg[(size_t)(kt + 32 + bk + 7) * TWO_D];
        }

        __syncthreads();   // single barrier per step (dbuf makes 2nd redundant)

        bf16x8 af0 = *(bf16x8*)&Al[p][(wm + lm) * LSTR + q * 8];
        bf16x8 af1 = *(bf16x8*)&Al[p][(wm + 16 + lm) * LSTR + q * 8];
        bf16x8 bfr[4];
        #pragma unroll
        for (int f = 0; f < 4; f++)
            bfr[f] = *(bf16x8*)&Bl[p][(f * 16 + lm) * LSTR + q * 8];

        #pragma unroll
        for (int f = 0; f < 4; f++) {
            acc[0][f] = __builtin_amdgcn_mfma_f32_16x16x32_bf16(af0, bfr[f], acc[0][f], 0, 0, 0);
            acc[1][f] = __builtin_amdgcn_mfma_f32_16x16x32_bf16(af1, bfr[f], acc[1][f], 0, 0, 0);
        }

        p ^= 1;
    }

    #pragma unroll
    for (int i = 0; i < 2; i++)
        #pragma unroll
        for (int f = 0; f < 4; f++)
            #pragma unroll
            for (int e = 0; e < 4; e++) {
                int row = bm * 128 + wm + i * 16 + q * 4 + e;
                int col = bn * 64 + f * 16 + lm;
                P[(size_t)row * TWO_D + col] = acc[i][f][e];
            }
}

// ---------------------------------------------------------------------------
// Kernel 2 (R5 form): fused (split-K reduce + bias) + causal conv K=3 + SiLU
// + gate + delta/B/C MFMA projection (pipelined Bl, 1 barrier/step).
// 512 blocks = 8 XCD x 16 bm x 4 bn.
// ---------------------------------------------------------------------------
__global__ __launch_bounds__(256) void convproj_mfma(
    const float* __restrict__ P0,      // [M,256]
    const float* __restrict__ P1,      // [M,256]
    const float* __restrict__ b_up,    // [256]
    const float* __restrict__ conv_w,  // [D,3]
    const float* __restrict__ conv_b,  // [D]
    const float* __restrict__ W_delta, const float* __restrict__ b_delta,
    const float* __restrict__ W_B,     const float* __restrict__ b_B,
    const float* __restrict__ W_C,     const float* __restrict__ b_C,
    unsigned short* __restrict__ x,    // [M,128] bf16 (for scan)
    float* __restrict__ u,             // [M,256] (right half written)
    unsigned short* __restrict__ delta,// [M,128] bf16
    unsigned short* __restrict__ Bm,   // [M,64] bf16
    unsigned short* __restrict__ Cm)   // [M,64] bf16
{
    __shared__ float uu[66 * 128];     // rows -2..63, conv cols
    __shared__ short Xl[64 * LSTRX];   // bf16 A operand, full K=128
    __shared__ short Bl[2][64 * LSTR];

    int lid = blockIdx.x;
    int xcd = lid & 7;
    int slot = lid >> 3;
    int bm = xcd * 16 + (slot >> 2);
    int bn = slot & 3;
    int tid = threadIdx.x;

    bool seq_start = (bm & 31) == 0;   // tile starts at t==0 of a sequence

    // ---- stage uu = P0+P1+b_up for rows bm*64-2 .. bm*64+63, cols 0..127 ----
    #pragma unroll
    for (int i = 0; i < 9; i++) {
        int fi = tid + i * 256;        // float4 index, 2112 total
        if (fi < 2112) {
            int row = fi >> 5;         // 0..65
            int c4 = (fi & 31) * 4;    // 0..124
            int gr = bm * 64 + row - 2;
            float4 v;
            if (seq_start && row < 2) {
                v = make_float4(0.f, 0.f, 0.f, 0.f);
            } else {
                size_t gi = (size_t)gr * TWO_D + c4;
                float4 p0 = *(const float4*)&P0[gi];
                float4 p1 = *(const float4*)&P1[gi];
                float4 bb = *(const float4*)&b_up[c4];
                v = make_float4(p0.x + p1.x + bb.x, p0.y + p1.y + bb.y,
                                p0.z + p1.z + bb.z, p0.w + p1.w + bb.w);
            }
            *(float4*)&uu[fi * 4] = v;
        }
    }

    // ---- gate half (bn==1 writes u[:,128:256]) ----
    if (bn == 1) {
        #pragma unroll
        for (int i = 0; i < 8; i++) {
            int fi = tid + i * 256;    // 2048 float4s
            int row = fi >> 5;
            int c4 = (fi & 31) * 4 + 128;
            int gr = bm * 64 + row;
            size_t gi = (size_t)gr * TWO_D + c4;
            float4 p0 = *(const float4*)&P0[gi];
            float4 p1 = *(const float4*)&P1[gi];
            float4 bb = *(const float4*)&b_up[c4];
            *(float4*)&u[gi] = make_float4(p0.x + p1.x + bb.x, p0.y + p1.y + bb.y,
                                           p0.z + p1.z + bb.z, p0.w + p1.w + bb.w);
        }
    }
    __syncthreads();

    // ---- conv + silu -> Xl (bf16) and (bn==0) x global (bf16) ----
    #pragma unroll
    for (int i = 0; i < 8; i++) {
        int fi = tid + i * 256;        // 2048 float4 outputs
        int row = fi >> 5;             // 0..63
        int c4 = (fi & 31) * 4;
        float4 v2 = *(const float4*)&uu[(row + 2) * 128 + c4];
        float4 v1 = *(const float4*)&uu[(row + 1) * 128 + c4];
        float4 v0 = *(const float4*)&uu[(row + 0) * 128 + c4];
        float4 z;
        {
            float w0 = conv_w[(c4 + 0) * 3 + 0], w1 = conv_w[(c4 + 0) * 3 + 1], w2 = conv_w[(c4 + 0) * 3 + 2];
            z.x = silu_f(fmaf(w0, v0.x, fmaf(w1, v1.x, fmaf(w2, v2.x, conv_b[c4 + 0]))));
        }
        {
            float w0 = conv_w[(c4 + 1) * 3 + 0], w1 = conv_w[(c4 + 1) * 3 + 1], w2 = conv_w[(c4 + 1) * 3 + 2];
            z.y = silu_f(fmaf(w0, v0.y, fmaf(w1, v1.y, fmaf(w2, v2.y, conv_b[c4 + 1]))));
        }
        {
            float w0 = conv_w[(c4 + 2) * 3 + 0], w1 = conv_w[(c4 + 2) * 3 + 1], w2 = conv_w[(c4 + 2) * 3 + 2];
            z.z = silu_f(fmaf(w0, v0.z, fmaf(w1, v1.z, fmaf(w2, v2.z, conv_b[c4 + 2]))));
        }
        {
            float w0 = conv_w[(c4 + 3) * 3 + 0], w1 = conv_w[(c4 + 3) * 3 + 1], w2 = conv_w[(c4 + 3) * 3 + 2];
            z.w = silu_f(fmaf(w0, v0.w, fmaf(w1, v1.w, fmaf(w2, v2.w, conv_b[c4 + 3]))));
        }
        short4 zb;
        zb.x = f2bf(z.x); zb.y = f2bf(z.y); zb.z = f2bf(z.z); zb.w = f2bf(z.w);
        *(short4*)&Xl[row * LSTRX + c4] = zb;
        if (bn == 0) {
            int gr = bm * 64 + row;
            *(short4*)&x[(size_t)gr * D_ + c4] = zb;
        }
    }

    // ---- weight select ----
    const float* Wsel; const float* bsel; int wstride;
    if (bn < 2)       { Wsel = W_delta + bn * 64; bsel = b_delta + bn * 64; wstride = 128; }
    else if (bn == 2) { Wsel = W_B;               bsel = b_B;               wstride = 64;  }
    else              { Wsel = W_C;               bsel = b_C;               wstride = 64;  }

    int w = tid >> 6, l = tid & 63;
    int lm = l & 15, q = l >> 4;
    int wm = (w & 1) * 32, wn = (w >> 1) * 32;

    f32x4 acc00 = {0,0,0,0}, acc01 = {0,0,0,0}, acc10 = {0,0,0,0}, acc11 = {0,0,0,0};

    int bcol = tid & 63, bk = (tid >> 6) * 8;
    const float* Wg = Wsel + bcol;

    // preload step 0 W into regs (no pre-loop barrier needed: first in-loop
    // barrier covers the Xl writes above)
    float w0 = Wg[(size_t)(bk + 0) * wstride];
    float w1 = Wg[(size_t)(bk + 1) * wstride];
    float w2 = Wg[(size_t)(bk + 2) * wstride];
    float w3 = Wg[(size_t)(bk + 3) * wstride];
    float w4 = Wg[(size_t)(bk + 4) * wstride];
    float w5 = Wg[(size_t)(bk + 5) * wstride];
    float w6 = Wg[(size_t)(bk + 6) * wstride];
    float w7 = Wg[(size_t)(bk + 7) * wstride];

    int p = 0;
    for (int kt = 0; kt < 128; kt += 32) {
        *(bf16x8*)&Bl[p][bcol * LSTR + bk] =
            pack8(make_float4(w0, w1, w2, w3), make_float4(w4, w5, w6, w7));

        if (kt + 32 < 128) {
            w0 = Wg[(size_t)(kt + 32 + bk + 0) * wstride];
            w1 = Wg[(size_t)(kt + 32 + bk + 1) * wstride];
            w2 = Wg[(size_t)(kt + 32 + bk + 2) * wstride];
            w3 = Wg[(size_t)(kt + 32 + bk + 3) * wstride];
            w4 = Wg[(size_t)(kt + 32 + bk + 4) * wstride];
            w5 = Wg[(size_t)(kt + 32 + bk + 5) * wstride];
            w6 = Wg[(size_t)(kt + 32 + bk + 6) * wstride];
            w7 = Wg[(size_t)(kt + 32 + bk + 7) * wstride];
        }

        __syncthreads();

        bf16x8 af0 = *(bf16x8*)&Xl[(wm + lm) * LSTRX + kt + q * 8];
        bf16x8 af1 = *(bf16x8*)&Xl[(wm + 16 + lm) * LSTRX + kt + q * 8];
        bf16x8 bf0 = *(bf16x8*)&Bl[p][(wn + lm) * LSTR + q * 8];
        bf16x8 bf1 = *(bf16x8*)&Bl[p][(wn + 16 + lm) * LSTR + q * 8];

        acc00 = __builtin_amdgcn_mfma_f32_16x16x32_bf16(af0, bf0, acc00, 0, 0, 0);
        acc01 = __builtin_amdgcn_mfma_f32_16x16x32_bf16(af0, bf1, acc01, 0, 0, 0);
        acc10 = __builtin_amdgcn_mfma_f32_16x16x32_bf16(af1, bf0, acc10, 0, 0, 0);
        acc11 = __builtin_amdgcn_mfma_f32_16x16x32_bf16(af1, bf1, acc11, 0, 0, 0);

        p ^= 1;
    }

    #pragma unroll
    for (int i = 0; i < 4; i++) {
        int r0 = bm * 64 + wm + q * 4 + i;
        int r1 = r0 + 16;
        int c0 = wn + lm;
        int c1 = c0 + 16;
        float v00 = acc00[i] + bsel[c0];
        float v01 = acc01[i] + bsel[c1];
        float v10 = acc10[i] + bsel[c0];
        float v11 = acc11[i] + bsel[c1];
        if (bn < 2) {
            int cc0 = bn * 64 + c0, cc1 = bn * 64 + c1;
            delta[(size_t)r0 * D_ + cc0] = (unsigned short)f2bf(softplus_f(v00));
            delta[(size_t)r0 * D_ + cc1] = (unsigned short)f2bf(softplus_f(v01));
            delta[(size_t)r1 * D_ + cc0] = (unsigned short)f2bf(softplus_f(v10));
            delta[(size_t)r1 * D_ + cc1] = (unsigned short)f2bf(softplus_f(v11));
        } else if (bn == 2) {
            Bm[(size_t)r0 * N_ + c0] = (unsigned short)f2bf(v00);
            Bm[(size_t)r0 * N_ + c1] = (unsigned short)f2bf(v01);
            Bm[(size_t)r1 * N_ + c0] = (unsigned short)f2bf(v10);
            Bm[(size_t)r1 * N_ + c1] = (unsigned short)f2bf(v11);
        } else {
            Cm[(size_t)r0 * N_ + c0] = (unsigned short)f2bf(v00);
            Cm[(size_t)r0 * N_ + c1] = (unsigned short)f2bf(v01);
            Cm[(size_t)r1 * N_ + c0] = (unsigned short)f2bf(v10);
            Cm[(size_t)r1 * N_ + c1] = (unsigned short)f2bf(v11);
        }
    }
}

// ---------------------------------------------------------------------------
// Kernel 3a: summary pass. LDS-staged chunk tiles (R3 scheme). NC=64.
// ---------------------------------------------------------------------------
__global__ __launch_bounds__(256) void scan_sumA(
    const unsigned short* __restrict__ delta,   // [M,D] bf16
    const unsigned short* __restrict__ x,       // [M,D] bf16
    const unsigned short* __restrict__ Bm,      // [M,N] bf16
    const float* __restrict__ A_log,            // [D,N]
    float* __restrict__ ch_aprod,               // [B,D,NC,N]
    float* __restrict__ ch_h)                   // [B,D,NC,N]
{
    constexpr int TCt = L_ >> LNC;              // 32
    __shared__ unsigned short ld_d[TCt * 16];
    __shared__ unsigned short ld_x[TCt * 16];
    __shared__ unsigned short ld_b[TCt * 64];

    int blk = blockIdx.x;              // 2048 = 4 b x 8 dqg x 64 c
    int c = blk & (NC - 1);
    int dqg = (blk >> LNC) & 7;
    int b = blk >> (LNC + 3);
    int tid = threadIdx.x;
    int wv = tid >> 6;
    int l = tid & 63;
    int g = l >> 4, j = l & 15;
    int d0 = dqg * 16;
    int d = d0 + wv * 4 + g;
    int dloc = wv * 4 + g;

    size_t row0 = (size_t)b * L_ + c * TCt;

    {
        int t = (tid & 127) >> 2;
        int c4 = (tid & 3) * 4;
        const unsigned short* src = (tid < 128) ? delta : x;
        unsigned short* dst = (tid < 128) ? ld_d : ld_x;
        *(u16x4*)&dst[t * 16 + c4] = *(const u16x4*)&src[(row0 + t) * D_ + d0 + c4];
    }
    {
        int t = tid >> 3;
        int c8 = (tid & 7) * 8;
        *(bf16x8*)&ld_b[t * 64 + c8] = *(const bf16x8*)&Bm[(row0 + t) * N_ + c8];
    }

    const float LOG2E = 1.44269504089f;
    float4 Ar = *(const float4*)&A_log[d * N_ + j * 4];
    float Ai0 = -__expf(Ar.x) * LOG2E;
    float Ai1 = -__expf(Ar.y) * LOG2E;
    float Ai2 = -__expf(Ar.z) * LOG2E;
    float Ai3 = -__expf(Ar.w) * LOG2E;

    __syncthreads();

    float h0 = 0, h1 = 0, h2 = 0, h3 = 0;
    float S = 0;

    #pragma unroll 8
    for (int t = 0; t < TCt; t++) {
        float dl = bf2f(ld_d[t * 16 + dloc]);
        float xv = bf2f(ld_x[t * 16 + dloc]);
        u16x4 bv = *(const u16x4*)&ld_b[t * 64 + j * 4];
        float e0 = exp2f(dl * Ai0);
        float e1 = exp2f(dl * Ai1);
        float e2 = exp2f(dl * Ai2);
        float e3 = exp2f(dl * Ai3);
        float dbx = dl * xv;
        h0 = fmaf(e0, h0, dbx * bf2f(bv[0]));
        h1 = fmaf(e1, h1, dbx * bf2f(bv[1]));
        h2 = fmaf(e2, h2, dbx * bf2f(bv[2]));
        h3 = fmaf(e3, h3, dbx * bf2f(bv[3]));
        S += dl;
    }

    size_t ci = (((size_t)b * D_ + d) * NC + c) * N_ + j * 4;
    *(float4*)&ch_aprod[ci] = make_float4(exp2f(Ai0 * S), exp2f(Ai1 * S),
                                          exp2f(Ai2 * S), exp2f(Ai3 * S));
    *(float4*)&ch_h[ci]     = make_float4(h0, h1, h2, h3);
}

// ---------------------------------------------------------------------------
// Kernel 3b: serial prefix over NC chunk summaries, per (b,d,n).
// ---------------------------------------------------------------------------
__global__ __launch_bounds__(64) void scan_prefix(
    float* __restrict__ aprod_hin,     // in: chunk aprod; out: hin
    const float* __restrict__ ch_h)
{
    int idx = blockIdx.x * 64 + threadIdx.x;    // B*D*N = 32768 exact
    int n = idx & 63;
    int rest = idx >> 6;
    size_t base = (size_t)rest * NC * N_ + n;
    float h = 0.0f;
    #pragma unroll 8
    for (int c = 0; c < NC; c++) {
        size_t o = base + (size_t)c * N_;
        float a  = aprod_hin[o];
        float hh = ch_h[o];
        aprod_hin[o] = h;
        h = fmaf(a, h, hh);
    }
}

// ---------------------------------------------------------------------------
// Kernel 3c: output pass. LDS-staged tiles; SiLU gate applied once; bf16
// `gated` written coalesced. (R3 scheme, NC=64.)
// ---------------------------------------------------------------------------
__global__ __launch_bounds__(256) void scan_outB(
    const unsigned short* __restrict__ delta,   // [M,D] bf16
    const unsigned short* __restrict__ x,       // [M,D] bf16
    const unsigned short* __restrict__ Bm,      // [M,N] bf16
    const unsigned short* __restrict__ Cm,      // [M,N] bf16
    const float* __restrict__ A_log,            // [D,N]
    const float* __restrict__ D_skip,           // [D]
    const float* __restrict__ hin,              // [B,D,NC,N]
    const float* __restrict__ u,                // [M,256] right-half gates
    short* __restrict__ gated)                  // [M,128] bf16: y * silu(u_r)
{
    constexpr int TCt = L_ >> LNC;              // 32
    __shared__ unsigned short ld_d[TCt * 16];
    __shared__ unsigned short ld_x[TCt * 16];
    __shared__ unsigned short ld_b[TCt * 64];
    __shared__ unsigned short ld_c[TCt * 64];
    __shared__ float yl[TCt * 16];

    int blk = blockIdx.x;              // 2048 = 4 b x 8 dqg x 64 c
    int c = blk & (NC - 1);
    int dqg = (blk >> LNC) & 7;
    int b = blk >> (LNC + 3);
    int tid = threadIdx.x;
    int wv = tid >> 6;
    int l = tid & 63;
    int g = l >> 4, j = l & 15;
    int d0 = dqg * 16;
    int d = d0 + wv * 4 + g;
    int dloc = wv * 4 + g;

    size_t row0 = (size_t)b * L_ + c * TCt;

    {
        int t = (tid & 127) >> 2;
        int c4 = (tid & 3) * 4;
        const unsigned short* src = (tid < 128) ? delta : x;
        unsigned short* dst = (tid < 128) ? ld_d : ld_x;
        *(u16x4*)&dst[t * 16 + c4] = *(const u16x4*)&src[(row0 + t) * D_ + d0 + c4];
    }
    {
        int t = tid >> 3;
        int c8 = (tid & 7) * 8;
        *(bf16x8*)&ld_b[t * 64 + c8] = *(const bf16x8*)&Bm[(row0 + t) * N_ + c8];
        *(bf16x8*)&ld_c[t * 64 + c8] = *(const bf16x8*)&Cm[(row0 + t) * N_ + c8];
    }

    const float LOG2E = 1.44269504089f;
    float4 Ar = *(const float4*)&A_log[d * N_ + j * 4];
    float Ai0 = -__expf(Ar.x) * LOG2E;
    float Ai1 = -__expf(Ar.y) * LOG2E;
    float Ai2 = -__expf(Ar.z) * LOG2E;
    float Ai3 = -__expf(Ar.w) * LOG2E;
    float dsk = D_skip[d];

    float4 hv = *(const float4*)&hin[(((size_t)b * D_ + d) * NC + c) * N_ + j * 4];
    float h0 = hv.x, h1 = hv.y, h2 = hv.z, h3 = hv.w;

    __syncthreads();

    #pragma unroll 8
    for (int t = 0; t < TCt; t++) {
        float dl = bf2f(ld_d[t * 16 + dloc]);
        float xv = bf2f(ld_x[t * 16 + dloc]);
        u16x4 bv = *(const u16x4*)&ld_b[t * 64 + j * 4];
        u16x4 cv = *(const u16x4*)&ld_c[t * 64 + j * 4];
        float e0 = exp2f(dl * Ai0);
        float e1 = exp2f(dl * Ai1);
        float e2 = exp2f(dl * Ai2);
        float e3 = exp2f(dl * Ai3);
        float dbx = dl * xv;
        h0 = fmaf(e0, h0, dbx * bf2f(bv[0]));
        h1 = fmaf(e1, h1, dbx * bf2f(bv[1]));
        h2 = fmaf(e2, h2, dbx * bf2f(bv[2]));
        h3 = fmaf(e3, h3, dbx * bf2f(bv[3]));
        float p = fmaf(h0, bf2f(cv[0]), fmaf(h1, bf2f(cv[1]),
                  fmaf(h2, bf2f(cv[2]), h3 * bf2f(cv[3]))));
        p += __shfl_xor(p, 1, 64);
        p += __shfl_xor(p, 2, 64);
        p += __shfl_xor(p, 4, 64);
        p += __shfl_xor(p, 8, 64);
        if (j == 0) yl[t * 16 + dloc] = fmaf(dsk, xv, p);
    }

    __syncthreads();

    if (tid < 128) {
        int t = tid >> 2;              // 0..31
        int c4 = (tid & 3) * 4;        // 0,4,8,12
        size_t row = row0 + t;
        float4 yv = *(float4*)&yl[t * 16 + c4];
        float4 gv = *(const float4*)&u[row * TWO_D + 128 + d0 + c4];
        short4 o;
        o.x = f2bf(yv.x * silu_f(gv.x));
        o.y = f2bf(yv.y * silu_f(gv.y));
        o.z = f2bf(yv.z * silu_f(gv.z));
        o.w = f2bf(yv.w * silu_f(gv.w));
        *(short4*)&gated[row * D_ + d0 + c4] = o;
    }
}

// ---------------------------------------------------------------------------
// Kernel 4 (R5 form): out = gated @ W_down + b_down. Pipelined dbuf LDS,
// reg prefetch, one barrier per step.
// ---------------------------------------------------------------------------
__global__ __launch_bounds__(256) void gemm_down_mfma(
    const short* __restrict__ gated, // [M,128] bf16
    const float* __restrict__ W,     // [128,1024]
    const float* __restrict__ bias,  // [1024]
    float* __restrict__ out)         // [M,1024]
{
    __shared__ short Al[2][64 * LSTR];
    __shared__ short Bl[2][64 * LSTR];

    int lid = blockIdx.x;            // 0..2047
    int xcd = lid & 7;
    int slot = lid >> 3;
    int bm = xcd * 16 + (slot >> 4);
    int bn = slot & 15;

    int tid = threadIdx.x;
    int w = tid >> 6, l = tid & 63;
    int lm = l & 15, q = l >> 4;
    int wm = (w & 1) * 32, wn = (w >> 1) * 32;

    f32x4 acc00 = {0,0,0,0}, acc01 = {0,0,0,0}, acc10 = {0,0,0,0}, acc11 = {0,0,0,0};

    int ar = tid >> 2, ak = (tid & 3) * 8;
    int bcol = tid & 63, bk = (tid >> 6) * 8;

    const short* Gg = gated + (size_t)(bm * 64 + ar) * D_ + ak;
    const float* Wg = W + (size_t)bn * 64 + bcol;

    // preload step 0
    bf16x8 av = *(const bf16x8*)(Gg);
    float w0 = Wg[(size_t)(bk + 0) * R_];
    float w1 = Wg[(size_t)(bk + 1) * R_];
    float w2 = Wg[(size_t)(bk + 2) * R_];
    float w3 = Wg[(size_t)(bk + 3) * R_];
    float w4 = Wg[(size_t)(bk + 4) * R_];
    float w5 = Wg[(size_t)(bk + 5) * R_];
    float w6 = Wg[(size_t)(bk + 6) * R_];
    float w7 = Wg[(size_t)(bk + 7) * R_];

    int p = 0;
    for (int kt = 0; kt < 128; kt += 32) {
        *(bf16x8*)&Al[p][ar * LSTR + ak] = av;
        *(bf16x8*)&Bl[p][bcol * LSTR + bk] =
            pack8(make_float4(w0, w1, w2, w3), make_float4(w4, w5, w6, w7));

        if (kt + 32 < 128) {
            av = *(const bf16x8*)(Gg + kt + 32);
            w0 = Wg[(size_t)(kt + 32 + bk + 0) * R_];
            w1 = Wg[(size_t)(kt + 32 + bk + 1) * R_];
            w2 = Wg[(size_t)(kt + 32 + bk + 2) * R_];
            w3 = Wg[(size_t)(kt + 32 + bk + 3) * R_];
            w4 = Wg[(size_t)(kt + 32 + bk + 4) * R_];
            w5 = Wg[(size_t)(kt + 32 + bk + 5) * R_];
            w6 = Wg[(size_t)(kt + 32 + bk + 6) * R_];
            w7 = Wg[(size_t)(kt + 32 + bk + 7) * R_];
        }

        __syncthreads();

        bf16x8 af0 = *(bf16x8*)&Al[p][(wm + lm) * LSTR + q * 8];
        bf16x8 af1 = *(bf16x8*)&Al[p][(wm + 16 + lm) * LSTR + q * 8];
        bf16x8 bf0 = *(bf16x8*)&Bl[p][(wn + lm) * LSTR + q * 8];
        bf16x8 bf1 = *(bf16x8*)&Bl[p][(wn + 16 + lm) * LSTR + q * 8];

        acc00 = __builtin_amdgcn_mfma_f32_16x16x32_bf16(af0, bf0, acc00, 0, 0, 0);
        acc01 = __builtin_amdgcn_mfma_f32_16x16x32_bf16(af0, bf1, acc01, 0, 0, 0);
        acc10 = __builtin_amdgcn_mfma_f32_16x16x32_bf16(af1, bf0, acc10, 0, 0, 0);
        acc11 = __builtin_amdgcn_mfma_f32_16x16x32_bf16(af1, bf1, acc11, 0, 0, 0);

        p ^= 1;
    }

    #pragma unroll
    for (int i = 0; i < 4; i++) {
        int r0 = bm * 64 + wm + q * 4 + i;
        int r1 = r0 + 16;
        int c0 = bn * 64 + wn + lm;
        int c1 = c0 + 16;
        out[(size_t)r0 * R_ + c0] = acc00[i] + bias[c0];
        out[(size_t)r0 * R_ + c1] = acc01[i] + bias[c1];
        out[(size_t)r1 * R_ + c0] = acc10[i] + bias[c0];
        out[(size_t)r1 * R_ + c1] = acc11[i] + bias[c1];
    }
}

// ---------------------------------------------------------------------------
extern "C" void kernel_launch(void* const* d_in, const int* in_sizes, int n_in,
                              void* d_out, int out_size, void* d_ws, size_t ws_size,
                              hipStream_t stream)
{
    const float* up_x    = (const float*)d_in[0];
    const float* W_up    = (const float*)d_in[1];
    const float* b_up    = (const float*)d_in[2];
    const float* conv_w  = (const float*)d_in[3];
    const float* conv_b  = (const float*)d_in[4];
    const float* W_delta = (const float*)d_in[5];
    const float* b_delta = (const float*)d_in[6];
    const float* W_B     = (const float*)d_in[7];
    const float* b_B     = (const float*)d_in[8];
    const float* W_C     = (const float*)d_in[9];
    const float* b_C     = (const float*)d_in[10];
    const float* A_log   = (const float*)d_in[11];
    const float* D_skip  = (const float*)d_in[12];
    const float* W_down  = (const float*)d_in[13];
    const float* b_down  = (const float*)d_in[14];

    float* out = (float*)d_out;
    float* ws  = (float*)d_ws;

    // workspace layout (all regions DEDICATED, 16B-aligned):
    float* u = ws;                                       // fp32 [M,256]
    unsigned short* x16     = (unsigned short*)(u + (size_t)M_ * TWO_D);
    unsigned short* delta16 = x16     + (size_t)M_ * D_;
    unsigned short* Bm16    = delta16 + (size_t)M_ * D_;
    unsigned short* Cm16    = Bm16    + (size_t)M_ * N_;
    unsigned short* gated   = Cm16    + (size_t)M_ * N_;
    float* ch_aprod = (float*)(gated + (size_t)M_ * D_);
    float* ch_h     = ch_aprod + (size_t)B_ * D_ * NC * N_;
    float* P0       = ch_h     + (size_t)B_ * D_ * NC * N_;
    float* P1       = P0       + (size_t)M_ * TWO_D;

    // 1. split-K up-projection (pipelined, 1 barrier/K-step)
    gemm_up_splitk<<<512, 256, 0, stream>>>(up_x, W_up, P0, P1);

    // 2. fused reduce+bias+conv+silu+gate+delta/B/C projection (pipelined)
    convproj_mfma<<<512, 256, 0, stream>>>(
        P0, P1, b_up, conv_w, conv_b,
        W_delta, b_delta, W_B, b_B, W_C, b_C,
        x16, u, delta16, Bm16, Cm16);

    // 3. chunked scan: summaries -> prefix -> output
    scan_sumA<<<B_ * 8 * NC, 256, 0, stream>>>(
        delta16, x16, Bm16, A_log, ch_aprod, ch_h);
    scan_prefix<<<(B_ * D_ * N_) / 64, 64, 0, stream>>>(
        ch_aprod, ch_h);
    scan_outB<<<B_ * 8 * NC, 256, 0, stream>>>(
        delta16, x16, Bm16, Cm16, A_log, D_skip, ch_aprod, u, (short*)gated);

    // 4. down-projection GEMM (pipelined)
    gemm_down_mfma<<<2048, 256, 0, stream>>>(
        (const short*)gated, W_down, b_down, out);
}